// Round 1
// baseline (1508.428 us; speedup 1.0000x reference)
//
#include <hip/hip_runtime.h>
#include <math.h>

#define N_NODES_C 100000
#define N_EDGES_C 1600000
#define DIM 64
#define G3 192

// ---------------------------------------------------------------------------
// Phase 1: scatter-add edge features into aggr[receiver]
// ---------------------------------------------------------------------------
__device__ __forceinline__ void atomic_add_f32(float* p, float v) {
    // AGENT scope + relaxed -> native global_atomic_add_f32 on gfx950
    __hip_atomic_fetch_add(p, v, __ATOMIC_RELAXED, __HIP_MEMORY_SCOPE_AGENT);
}

__global__ void scatter_kernel(const float* __restrict__ edges,
                               const int* __restrict__ receivers,
                               float* __restrict__ aggr) {
    int idx = blockIdx.x * blockDim.x + threadIdx.x;   // float4-chunk index
    if (idx >= N_EDGES_C * 16) return;                 // 25.6M chunks
    int e = idx >> 4;
    int c = (idx & 15) << 2;
    const float4 v = *reinterpret_cast<const float4*>(edges + (size_t)e * DIM + c);
    int r = receivers[e];
    float* dst = aggr + (size_t)r * DIM + c;
    atomic_add_f32(dst + 0, v.x);
    atomic_add_f32(dst + 1, v.y);
    atomic_add_f32(dst + 2, v.z);
    atomic_add_f32(dst + 3, v.w);
}

// ---------------------------------------------------------------------------
// Phase 2: GRU cell update.
// Block = 256 threads (4 waves), handles NT=32 nodes. Lane d computes output
// feature d for NPW=8 nodes (register-amortizes weight LDS reads 8x).
// Two passes over one 52KB LDS weight buffer: pass A = w_ih (gi),
// pass B = w_hh (gh). Node rows staged in LDS, read as wave-broadcasts.
// ---------------------------------------------------------------------------
#define NT 32
#define NPW 8
#define WPAD 68   // padded row stride (floats); 68*4B = 272B, 16B-aligned

__global__ __launch_bounds__(256, 2)
void gru_kernel(const float* __restrict__ aggr,
                const float* __restrict__ nodes,
                const float* __restrict__ w_ih,
                const float* __restrict__ w_hh,
                const float* __restrict__ b_ih,
                const float* __restrict__ b_hh,
                float* __restrict__ out) {
    __shared__ float wlds[G3 * WPAD];   // 52.2 KB
    __shared__ float rows[NT * DIM];    // 8 KB

    const int tid  = threadIdx.x;
    const int lane = tid & 63;
    const int wave = tid >> 6;
    const int nb   = blockIdx.x * NT;
    const int myn0 = wave * NPW;

    float accA[NPW][3];   // gi: r,z,n
    float accB[NPW][3];   // gh: r,z,n

    // ---- stage w_ih (192x64 -> padded) + aggr rows
    {
        const float4* src = reinterpret_cast<const float4*>(w_ih);
        #pragma unroll
        for (int i = 0; i < 12; ++i) {
            int t = tid + i * 256;               // 3072 float4s total
            float4 v = src[t];
            int row = t >> 4;
            int col = (t & 15) << 2;
            *reinterpret_cast<float4*>(&wlds[row * WPAD + col]) = v;
        }
        #pragma unroll
        for (int i = 0; i < 2; ++i) {
            int t = tid + i * 256;               // 512 float4s
            int n = t >> 4, c = (t & 15) << 2;
            *reinterpret_cast<float4*>(&rows[n * DIM + c]) =
                *reinterpret_cast<const float4*>(&aggr[(size_t)(nb + n) * DIM + c]);
        }
    }
    __syncthreads();

    // ---- pass A: gi = aggr @ w_ih.T
    #pragma unroll
    for (int n = 0; n < NPW; ++n) { accA[n][0] = 0.f; accA[n][1] = 0.f; accA[n][2] = 0.f; }
    #pragma unroll 4
    for (int ks = 0; ks < 16; ++ks) {
        const int k = ks * 4;
        float4 wr = *reinterpret_cast<const float4*>(&wlds[lane * WPAD + k]);
        float4 wz = *reinterpret_cast<const float4*>(&wlds[(64 + lane) * WPAD + k]);
        float4 wn = *reinterpret_cast<const float4*>(&wlds[(128 + lane) * WPAD + k]);
        #pragma unroll
        for (int n = 0; n < NPW; ++n) {
            float4 a = *reinterpret_cast<const float4*>(&rows[(myn0 + n) * DIM + k]);
            accA[n][0] += a.x * wr.x + a.y * wr.y + a.z * wr.z + a.w * wr.w;
            accA[n][1] += a.x * wz.x + a.y * wz.y + a.z * wz.z + a.w * wz.w;
            accA[n][2] += a.x * wn.x + a.y * wn.y + a.z * wn.z + a.w * wn.w;
        }
    }
    __syncthreads();

    // ---- restage: w_hh + node rows
    {
        const float4* src = reinterpret_cast<const float4*>(w_hh);
        #pragma unroll
        for (int i = 0; i < 12; ++i) {
            int t = tid + i * 256;
            float4 v = src[t];
            int row = t >> 4;
            int col = (t & 15) << 2;
            *reinterpret_cast<float4*>(&wlds[row * WPAD + col]) = v;
        }
        #pragma unroll
        for (int i = 0; i < 2; ++i) {
            int t = tid + i * 256;
            int n = t >> 4, c = (t & 15) << 2;
            *reinterpret_cast<float4*>(&rows[n * DIM + c]) =
                *reinterpret_cast<const float4*>(&nodes[(size_t)(nb + n) * DIM + c]);
        }
    }
    __syncthreads();

    // ---- pass B: gh = nodes @ w_hh.T
    #pragma unroll
    for (int n = 0; n < NPW; ++n) { accB[n][0] = 0.f; accB[n][1] = 0.f; accB[n][2] = 0.f; }
    #pragma unroll 4
    for (int ks = 0; ks < 16; ++ks) {
        const int k = ks * 4;
        float4 wr = *reinterpret_cast<const float4*>(&wlds[lane * WPAD + k]);
        float4 wz = *reinterpret_cast<const float4*>(&wlds[(64 + lane) * WPAD + k]);
        float4 wn = *reinterpret_cast<const float4*>(&wlds[(128 + lane) * WPAD + k]);
        #pragma unroll
        for (int n = 0; n < NPW; ++n) {
            float4 a = *reinterpret_cast<const float4*>(&rows[(myn0 + n) * DIM + k]);
            accB[n][0] += a.x * wr.x + a.y * wr.y + a.z * wr.z + a.w * wr.w;
            accB[n][1] += a.x * wz.x + a.y * wz.y + a.z * wz.z + a.w * wz.w;
            accB[n][2] += a.x * wn.x + a.y * wn.y + a.z * wn.z + a.w * wn.w;
        }
    }

    // ---- gates + output
    const float bir = b_ih[lane], biz = b_ih[64 + lane], bin_ = b_ih[128 + lane];
    const float bhr = b_hh[lane], bhz = b_hh[64 + lane], bhn = b_hh[128 + lane];
    #pragma unroll
    for (int n = 0; n < NPW; ++n) {
        const int node = nb + myn0 + n;
        const float h = rows[(myn0 + n) * DIM + lane];   // rows currently holds `nodes`
        const float ir = accA[n][0] + bir, iz = accA[n][1] + biz, inn = accA[n][2] + bin_;
        const float hr = accB[n][0] + bhr, hz = accB[n][1] + bhz, hn = accB[n][2] + bhn;
        const float r = 1.f / (1.f + __expf(-(ir + hr)));
        const float z = 1.f / (1.f + __expf(-(iz + hz)));
        float t = inn + r * hn;
        t = fminf(fmaxf(t, -15.f), 15.f);
        const float e2 = __expf(2.f * t);
        const float ng = (e2 - 1.f) / (e2 + 1.f);
        out[(size_t)node * DIM + lane] = (1.f - z) * ng + z * h;
    }
}

// ---------------------------------------------------------------------------
extern "C" void kernel_launch(void* const* d_in, const int* in_sizes, int n_in,
                              void* d_out, int out_size, void* d_ws, size_t ws_size,
                              hipStream_t stream) {
    const float* edges     = (const float*)d_in[0];
    const float* nodes     = (const float*)d_in[1];
    const int*   receivers = (const int*)d_in[2];
    const float* w_ih      = (const float*)d_in[3];
    const float* w_hh      = (const float*)d_in[4];
    const float* b_ih      = (const float*)d_in[5];
    const float* b_hh      = (const float*)d_in[6];
    float* out  = (float*)d_out;
    float* aggr = (float*)d_ws;   // N_NODES * DIM floats = 25.6 MB

    hipMemsetAsync(aggr, 0, (size_t)N_NODES_C * DIM * sizeof(float), stream);

    const int chunks = N_EDGES_C * 16;  // float4 chunks
    scatter_kernel<<<(chunks + 255) / 256, 256, 0, stream>>>(edges, receivers, aggr);

    gru_kernel<<<N_NODES_C / NT, 256, 0, stream>>>(aggr, nodes, w_ih, w_hh,
                                                   b_ih, b_hh, out);
}

// Round 2
// 576.549 us; speedup vs baseline: 2.6163x; 2.6163x over previous
//
#include <hip/hip_runtime.h>
#include <math.h>

#define N_NODES_C 100000
#define N_EDGES_C 1600000
#define DIM 64
#define G3 192
#define SCAN_B 1024
#define N_SCAN_BLOCKS ((N_NODES_C + SCAN_B - 1) / SCAN_B)   // 98

// ---------------------------------------------------------------------------
// Phase 1a: histogram receivers, record per-edge rank within its segment
// ---------------------------------------------------------------------------
__global__ void hist_kernel(const int* __restrict__ receivers,
                            int* __restrict__ count,
                            int* __restrict__ rank) {
    int e = blockIdx.x * blockDim.x + threadIdx.x;
    if (e >= N_EDGES_C) return;
    int r = receivers[e];
    rank[e] = __hip_atomic_fetch_add(&count[r], 1,
                                     __ATOMIC_RELAXED, __HIP_MEMORY_SCOPE_AGENT);
}

// ---------------------------------------------------------------------------
// Phase 1b: exclusive scan of count[] -> offsets[]  (3-kernel scan)
// ---------------------------------------------------------------------------
__global__ void scan1_kernel(const int* __restrict__ count,
                             int* __restrict__ offsets,
                             int* __restrict__ bsums) {
    __shared__ int wsum[16];
    const int gid  = blockIdx.x * SCAN_B + threadIdx.x;
    const int lane = threadIdx.x & 63;
    const int wv   = threadIdx.x >> 6;
    int c = (gid < N_NODES_C) ? count[gid] : 0;
    int x = c;
    #pragma unroll
    for (int o = 1; o < 64; o <<= 1) {
        int v = __shfl_up(x, o);
        if (lane >= o) x += v;
    }
    if (lane == 63) wsum[wv] = x;
    __syncthreads();
    if (wv == 0) {
        int s = (lane < 16) ? wsum[lane] : 0;
        #pragma unroll
        for (int o = 1; o < 16; o <<= 1) {
            int v = __shfl_up(s, o);
            if (lane >= o) s += v;
        }
        if (lane < 16) wsum[lane] = s;   // inclusive over waves
    }
    __syncthreads();
    int woff = (wv == 0) ? 0 : wsum[wv - 1];
    if (gid < N_NODES_C) offsets[gid] = woff + x - c;   // block-local exclusive
    if (threadIdx.x == SCAN_B - 1) bsums[blockIdx.x] = wsum[15];
}

__global__ void scan2_kernel(int* __restrict__ bsums) {
    // 98 entries, one block of 128 threads (2 waves)
    __shared__ int w0tot;
    const int i    = threadIdx.x;
    const int lane = threadIdx.x & 63;
    const int wv   = threadIdx.x >> 6;
    int c = (i < N_SCAN_BLOCKS) ? bsums[i] : 0;
    int x = c;
    #pragma unroll
    for (int o = 1; o < 64; o <<= 1) {
        int v = __shfl_up(x, o);
        if (lane >= o) x += v;
    }
    if (wv == 0 && lane == 63) w0tot = x;
    __syncthreads();
    int add = (wv == 1) ? w0tot : 0;
    if (i < N_SCAN_BLOCKS) bsums[i] = add + x - c;      // exclusive
}

__global__ void scan3_kernel(int* __restrict__ offsets,
                             const int* __restrict__ bsums) {
    int gid = blockIdx.x * SCAN_B + threadIdx.x;
    if (gid < N_NODES_C) offsets[gid] += bsums[blockIdx.x];
}

// ---------------------------------------------------------------------------
// Phase 1c: write permutation (CSR edge lists)
// ---------------------------------------------------------------------------
__global__ void permw_kernel(const int* __restrict__ receivers,
                             const int* __restrict__ offsets,
                             const int* __restrict__ rank,
                             int* __restrict__ perm) {
    int e = blockIdx.x * blockDim.x + threadIdx.x;
    if (e >= N_EDGES_C) return;
    perm[offsets[receivers[e]] + rank[e]] = e;
}

// ---------------------------------------------------------------------------
// Phase 2: fused gather-aggregate + GRU cell update.
// Block = 256 threads (4 waves), handles NT=32 nodes. Each wave gathers and
// aggregates the edge rows of its own 8 nodes into LDS, then lane d computes
// output feature d for those 8 nodes (weights register-amortized 8x).
// ---------------------------------------------------------------------------
#define NT 32
#define NPW 8
#define WPAD 68   // padded row stride (floats); 272B, 16B-aligned

__global__ __launch_bounds__(256, 2)
void gru_fused_kernel(const float* __restrict__ edges,
                      const int* __restrict__ perm,
                      const int* __restrict__ offsets,
                      const int* __restrict__ count,
                      const float* __restrict__ nodes,
                      const float* __restrict__ w_ih,
                      const float* __restrict__ w_hh,
                      const float* __restrict__ b_ih,
                      const float* __restrict__ b_hh,
                      float* __restrict__ out) {
    __shared__ float wlds[G3 * WPAD];   // 52.2 KB
    __shared__ float rows[NT * DIM];    // 8 KB

    const int tid  = threadIdx.x;
    const int lane = tid & 63;
    const int wave = tid >> 6;
    const int nb   = blockIdx.x * NT;
    const int myn0 = wave * NPW;

    float accA[NPW][3];
    float accB[NPW][3];

    // ---- stage w_ih + gather-aggregate this wave's 8 node rows
    {
        const float4* src = reinterpret_cast<const float4*>(w_ih);
        #pragma unroll
        for (int i = 0; i < 12; ++i) {
            int t = tid + i * 256;               // 3072 float4s total
            float4 v = src[t];
            int row = t >> 4;
            int col = (t & 15) << 2;
            *reinterpret_cast<float4*>(&wlds[row * WPAD + col]) = v;
        }
        #pragma unroll
        for (int n = 0; n < NPW; ++n) {
            const int node  = nb + myn0 + n;
            const int start = offsets[node];
            const int cnt   = count[node];
            float acc0 = 0.f, acc1 = 0.f;
            int i = 0;
            for (; i + 2 <= cnt; i += 2) {
                int e0 = perm[start + i];
                int e1 = perm[start + i + 1];
                acc0 += edges[(size_t)e0 * DIM + lane];
                acc1 += edges[(size_t)e1 * DIM + lane];
            }
            if (i < cnt) {
                int e0 = perm[start + i];
                acc0 += edges[(size_t)e0 * DIM + lane];
            }
            rows[(myn0 + n) * DIM + lane] = acc0 + acc1;
        }
    }
    __syncthreads();

    // ---- pass A: gi = aggr @ w_ih.T
    #pragma unroll
    for (int n = 0; n < NPW; ++n) { accA[n][0] = 0.f; accA[n][1] = 0.f; accA[n][2] = 0.f; }
    #pragma unroll 4
    for (int ks = 0; ks < 16; ++ks) {
        const int k = ks * 4;
        float4 wr = *reinterpret_cast<const float4*>(&wlds[lane * WPAD + k]);
        float4 wz = *reinterpret_cast<const float4*>(&wlds[(64 + lane) * WPAD + k]);
        float4 wn = *reinterpret_cast<const float4*>(&wlds[(128 + lane) * WPAD + k]);
        #pragma unroll
        for (int n = 0; n < NPW; ++n) {
            float4 a = *reinterpret_cast<const float4*>(&rows[(myn0 + n) * DIM + k]);
            accA[n][0] += a.x * wr.x + a.y * wr.y + a.z * wr.z + a.w * wr.w;
            accA[n][1] += a.x * wz.x + a.y * wz.y + a.z * wz.z + a.w * wz.w;
            accA[n][2] += a.x * wn.x + a.y * wn.y + a.z * wn.z + a.w * wn.w;
        }
    }
    __syncthreads();

    // ---- restage: w_hh + node rows
    {
        const float4* src = reinterpret_cast<const float4*>(w_hh);
        #pragma unroll
        for (int i = 0; i < 12; ++i) {
            int t = tid + i * 256;
            float4 v = src[t];
            int row = t >> 4;
            int col = (t & 15) << 2;
            *reinterpret_cast<float4*>(&wlds[row * WPAD + col]) = v;
        }
        #pragma unroll
        for (int i = 0; i < 2; ++i) {
            int t = tid + i * 256;
            int n = t >> 4, c = (t & 15) << 2;
            *reinterpret_cast<float4*>(&rows[n * DIM + c]) =
                *reinterpret_cast<const float4*>(&nodes[(size_t)(nb + n) * DIM + c]);
        }
    }
    __syncthreads();

    // ---- pass B: gh = nodes @ w_hh.T
    #pragma unroll
    for (int n = 0; n < NPW; ++n) { accB[n][0] = 0.f; accB[n][1] = 0.f; accB[n][2] = 0.f; }
    #pragma unroll 4
    for (int ks = 0; ks < 16; ++ks) {
        const int k = ks * 4;
        float4 wr = *reinterpret_cast<const float4*>(&wlds[lane * WPAD + k]);
        float4 wz = *reinterpret_cast<const float4*>(&wlds[(64 + lane) * WPAD + k]);
        float4 wn = *reinterpret_cast<const float4*>(&wlds[(128 + lane) * WPAD + k]);
        #pragma unroll
        for (int n = 0; n < NPW; ++n) {
            float4 a = *reinterpret_cast<const float4*>(&rows[(myn0 + n) * DIM + k]);
            accB[n][0] += a.x * wr.x + a.y * wr.y + a.z * wr.z + a.w * wr.w;
            accB[n][1] += a.x * wz.x + a.y * wz.y + a.z * wz.z + a.w * wz.w;
            accB[n][2] += a.x * wn.x + a.y * wn.y + a.z * wn.z + a.w * wn.w;
        }
    }

    // ---- gates + output
    const float bir = b_ih[lane], biz = b_ih[64 + lane], bin_ = b_ih[128 + lane];
    const float bhr = b_hh[lane], bhz = b_hh[64 + lane], bhn = b_hh[128 + lane];
    #pragma unroll
    for (int n = 0; n < NPW; ++n) {
        const int node = nb + myn0 + n;
        const float h = rows[(myn0 + n) * DIM + lane];   // rows holds `nodes`
        const float ir = accA[n][0] + bir, iz = accA[n][1] + biz, inn = accA[n][2] + bin_;
        const float hr = accB[n][0] + bhr, hz = accB[n][1] + bhz, hn = accB[n][2] + bhn;
        const float r = 1.f / (1.f + __expf(-(ir + hr)));
        const float z = 1.f / (1.f + __expf(-(iz + hz)));
        float t = inn + r * hn;
        t = fminf(fmaxf(t, -15.f), 15.f);
        const float e2 = __expf(2.f * t);
        const float ng = (e2 - 1.f) / (e2 + 1.f);
        out[(size_t)node * DIM + lane] = (1.f - z) * ng + z * h;
    }
}

// ---------------------------------------------------------------------------
extern "C" void kernel_launch(void* const* d_in, const int* in_sizes, int n_in,
                              void* d_out, int out_size, void* d_ws, size_t ws_size,
                              hipStream_t stream) {
    const float* edges     = (const float*)d_in[0];
    const float* nodes     = (const float*)d_in[1];
    const int*   receivers = (const int*)d_in[2];
    const float* w_ih      = (const float*)d_in[3];
    const float* w_hh      = (const float*)d_in[4];
    const float* b_ih      = (const float*)d_in[5];
    const float* b_hh      = (const float*)d_in[6];
    float* out = (float*)d_out;

    // workspace layout (ints)
    int* ws      = (int*)d_ws;
    int* count   = ws;                       // 100000
    int* offsets = ws + N_NODES_C;           // 100000
    int* rank    = ws + 2 * N_NODES_C;       // 1.6M
    int* perm    = rank + N_EDGES_C;         // 1.6M
    int* bsums   = perm + N_EDGES_C;         // 128
    // total ~13.6 MB

    hipMemsetAsync(count, 0, N_NODES_C * sizeof(int), stream);

    hist_kernel<<<(N_EDGES_C + 255) / 256, 256, 0, stream>>>(receivers, count, rank);
    scan1_kernel<<<N_SCAN_BLOCKS, SCAN_B, 0, stream>>>(count, offsets, bsums);
    scan2_kernel<<<1, 128, 0, stream>>>(bsums);
    scan3_kernel<<<N_SCAN_BLOCKS, SCAN_B, 0, stream>>>(offsets, bsums);
    permw_kernel<<<(N_EDGES_C + 255) / 256, 256, 0, stream>>>(receivers, offsets, rank, perm);

    gru_fused_kernel<<<N_NODES_C / NT, 256, 0, stream>>>(
        edges, perm, offsets, count, nodes, w_ih, w_hh, b_ih, b_hh, out);
}

// Round 3
// 330.686 us; speedup vs baseline: 4.5615x; 1.7435x over previous
//
#include <hip/hip_runtime.h>
#include <math.h>

#define N_NODES_C 100000
#define N_EDGES_C 1600000
#define DIM 64
#define G3 192
#define SCAN_B 1024
#define N_SCAN_BLOCKS ((N_NODES_C + SCAN_B - 1) / SCAN_B)   // 98

// ---------------------------------------------------------------------------
// Phase 1a: histogram receivers, record per-edge rank within its segment
// ---------------------------------------------------------------------------
__global__ void hist_kernel(const int* __restrict__ receivers,
                            int* __restrict__ count,
                            int* __restrict__ rank) {
    int e = blockIdx.x * blockDim.x + threadIdx.x;
    if (e >= N_EDGES_C) return;
    int r = receivers[e];
    rank[e] = __hip_atomic_fetch_add(&count[r], 1,
                                     __ATOMIC_RELAXED, __HIP_MEMORY_SCOPE_AGENT);
}

// ---------------------------------------------------------------------------
// Phase 1b: exclusive scan of count[] -> offsets[]
// ---------------------------------------------------------------------------
__global__ void scan1_kernel(const int* __restrict__ count,
                             int* __restrict__ offsets,
                             int* __restrict__ bsums) {
    __shared__ int wsum[16];
    const int gid  = blockIdx.x * SCAN_B + threadIdx.x;
    const int lane = threadIdx.x & 63;
    const int wv   = threadIdx.x >> 6;
    int c = (gid < N_NODES_C) ? count[gid] : 0;
    int x = c;
    #pragma unroll
    for (int o = 1; o < 64; o <<= 1) {
        int v = __shfl_up(x, o);
        if (lane >= o) x += v;
    }
    if (lane == 63) wsum[wv] = x;
    __syncthreads();
    if (wv == 0) {
        int s = (lane < 16) ? wsum[lane] : 0;
        #pragma unroll
        for (int o = 1; o < 16; o <<= 1) {
            int v = __shfl_up(s, o);
            if (lane >= o) s += v;
        }
        if (lane < 16) wsum[lane] = s;   // inclusive over waves
    }
    __syncthreads();
    int woff = (wv == 0) ? 0 : wsum[wv - 1];
    if (gid < N_NODES_C) offsets[gid] = woff + x - c;
    if (threadIdx.x == SCAN_B - 1) bsums[blockIdx.x] = wsum[15];
}

__global__ void scan2_kernel(int* __restrict__ bsums) {
    __shared__ int w0tot;
    const int i    = threadIdx.x;
    const int lane = threadIdx.x & 63;
    const int wv   = threadIdx.x >> 6;
    int c = (i < N_SCAN_BLOCKS) ? bsums[i] : 0;
    int x = c;
    #pragma unroll
    for (int o = 1; o < 64; o <<= 1) {
        int v = __shfl_up(x, o);
        if (lane >= o) x += v;
    }
    if (wv == 0 && lane == 63) w0tot = x;
    __syncthreads();
    int add = (wv == 1) ? w0tot : 0;
    if (i < N_SCAN_BLOCKS) bsums[i] = add + x - c;
}

__global__ void scan3_kernel(int* __restrict__ offsets,
                             const int* __restrict__ bsums) {
    int gid = blockIdx.x * SCAN_B + threadIdx.x;
    if (gid < N_NODES_C) offsets[gid] += bsums[blockIdx.x];
}

// ---------------------------------------------------------------------------
// Phase 1c: write permutation (CSR edge lists)
// ---------------------------------------------------------------------------
__global__ void permw_kernel(const int* __restrict__ receivers,
                             const int* __restrict__ offsets,
                             const int* __restrict__ rank,
                             int* __restrict__ perm) {
    int e = blockIdx.x * blockDim.x + threadIdx.x;
    if (e >= N_EDGES_C) return;
    perm[offsets[receivers[e]] + rank[e]] = e;
}

// ---------------------------------------------------------------------------
// Phase 2: gather-aggregate. One wave per node, no LDS -> max occupancy.
// 8 independent accumulator chains keep 8 coalesced 256B row-loads in flight.
// Writes aggr into d_out (N x D floats); GRU kernel consumes + overwrites it.
// ---------------------------------------------------------------------------
__global__ __launch_bounds__(256)
void gather_kernel(const float* __restrict__ edges,
                   const int* __restrict__ perm,
                   const int* __restrict__ offsets,
                   const int* __restrict__ count,
                   float* __restrict__ aggr) {
    const int w    = (blockIdx.x << 2) | (threadIdx.x >> 6);
    const int lane = threadIdx.x & 63;
    if (w >= N_NODES_C) return;
    const int start = offsets[w];
    const int cnt   = count[w];
    const int* __restrict__ p = perm + start;

    float a0 = 0.f, a1 = 0.f, a2 = 0.f, a3 = 0.f;
    float a4 = 0.f, a5 = 0.f, a6 = 0.f, a7 = 0.f;
    int i = 0;
    for (; i + 8 <= cnt; i += 8) {
        int e0 = p[i + 0], e1 = p[i + 1], e2 = p[i + 2], e3 = p[i + 3];
        int e4 = p[i + 4], e5 = p[i + 5], e6 = p[i + 6], e7 = p[i + 7];
        a0 += edges[(size_t)e0 * DIM + lane];
        a1 += edges[(size_t)e1 * DIM + lane];
        a2 += edges[(size_t)e2 * DIM + lane];
        a3 += edges[(size_t)e3 * DIM + lane];
        a4 += edges[(size_t)e4 * DIM + lane];
        a5 += edges[(size_t)e5 * DIM + lane];
        a6 += edges[(size_t)e6 * DIM + lane];
        a7 += edges[(size_t)e7 * DIM + lane];
    }
    if (i + 4 <= cnt) {
        int e0 = p[i + 0], e1 = p[i + 1], e2 = p[i + 2], e3 = p[i + 3];
        a0 += edges[(size_t)e0 * DIM + lane];
        a1 += edges[(size_t)e1 * DIM + lane];
        a2 += edges[(size_t)e2 * DIM + lane];
        a3 += edges[(size_t)e3 * DIM + lane];
        i += 4;
    }
    if (i + 2 <= cnt) {
        int e0 = p[i + 0], e1 = p[i + 1];
        a4 += edges[(size_t)e0 * DIM + lane];
        a5 += edges[(size_t)e1 * DIM + lane];
        i += 2;
    }
    if (i < cnt) {
        a6 += edges[(size_t)p[i] * DIM + lane];
    }
    aggr[(size_t)w * DIM + lane] = ((a0 + a1) + (a2 + a3)) + ((a4 + a5) + (a6 + a7));
}

// ---------------------------------------------------------------------------
// Phase 3: GRU cell update. Block = 256 threads / 32 nodes. aggr_out is read
// (this block's 32 rows staged to LDS) then overwritten with the result.
// ---------------------------------------------------------------------------
#define NT 32
#define NPW 8
#define WPAD 68   // padded row stride (floats); 272B, 16B-aligned

__global__ __launch_bounds__(256, 2)
void gru_kernel(float* aggr_out,
                const float* __restrict__ nodes,
                const float* __restrict__ w_ih,
                const float* __restrict__ w_hh,
                const float* __restrict__ b_ih,
                const float* __restrict__ b_hh) {
    __shared__ float wlds[G3 * WPAD];   // 52.2 KB
    __shared__ float rows[NT * DIM];    // 8 KB

    const int tid  = threadIdx.x;
    const int lane = tid & 63;
    const int wave = tid >> 6;
    const int nb   = blockIdx.x * NT;
    const int myn0 = wave * NPW;

    float accA[NPW][3];
    float accB[NPW][3];

    // ---- stage w_ih + this block's aggr rows
    {
        const float4* src = reinterpret_cast<const float4*>(w_ih);
        #pragma unroll
        for (int i = 0; i < 12; ++i) {
            int t = tid + i * 256;               // 3072 float4s
            float4 v = src[t];
            int row = t >> 4;
            int col = (t & 15) << 2;
            *reinterpret_cast<float4*>(&wlds[row * WPAD + col]) = v;
        }
        #pragma unroll
        for (int i = 0; i < 2; ++i) {
            int t = tid + i * 256;               // 512 float4s
            int n = t >> 4, c = (t & 15) << 2;
            *reinterpret_cast<float4*>(&rows[n * DIM + c]) =
                *reinterpret_cast<const float4*>(&aggr_out[(size_t)(nb + n) * DIM + c]);
        }
    }
    __syncthreads();

    // ---- pass A: gi = aggr @ w_ih.T
    #pragma unroll
    for (int n = 0; n < NPW; ++n) { accA[n][0] = 0.f; accA[n][1] = 0.f; accA[n][2] = 0.f; }
    #pragma unroll 4
    for (int ks = 0; ks < 16; ++ks) {
        const int k = ks * 4;
        float4 wr = *reinterpret_cast<const float4*>(&wlds[lane * WPAD + k]);
        float4 wz = *reinterpret_cast<const float4*>(&wlds[(64 + lane) * WPAD + k]);
        float4 wn = *reinterpret_cast<const float4*>(&wlds[(128 + lane) * WPAD + k]);
        #pragma unroll
        for (int n = 0; n < NPW; ++n) {
            float4 a = *reinterpret_cast<const float4*>(&rows[(myn0 + n) * DIM + k]);
            accA[n][0] += a.x * wr.x + a.y * wr.y + a.z * wr.z + a.w * wr.w;
            accA[n][1] += a.x * wz.x + a.y * wz.y + a.z * wz.z + a.w * wz.w;
            accA[n][2] += a.x * wn.x + a.y * wn.y + a.z * wn.z + a.w * wn.w;
        }
    }
    __syncthreads();

    // ---- restage: w_hh + node rows
    {
        const float4* src = reinterpret_cast<const float4*>(w_hh);
        #pragma unroll
        for (int i = 0; i < 12; ++i) {
            int t = tid + i * 256;
            float4 v = src[t];
            int row = t >> 4;
            int col = (t & 15) << 2;
            *reinterpret_cast<float4*>(&wlds[row * WPAD + col]) = v;
        }
        #pragma unroll
        for (int i = 0; i < 2; ++i) {
            int t = tid + i * 256;
            int n = t >> 4, c = (t & 15) << 2;
            *reinterpret_cast<float4*>(&rows[n * DIM + c]) =
                *reinterpret_cast<const float4*>(&nodes[(size_t)(nb + n) * DIM + c]);
        }
    }
    __syncthreads();

    // ---- pass B: gh = nodes @ w_hh.T
    #pragma unroll
    for (int n = 0; n < NPW; ++n) { accB[n][0] = 0.f; accB[n][1] = 0.f; accB[n][2] = 0.f; }
    #pragma unroll 4
    for (int ks = 0; ks < 16; ++ks) {
        const int k = ks * 4;
        float4 wr = *reinterpret_cast<const float4*>(&wlds[lane * WPAD + k]);
        float4 wz = *reinterpret_cast<const float4*>(&wlds[(64 + lane) * WPAD + k]);
        float4 wn = *reinterpret_cast<const float4*>(&wlds[(128 + lane) * WPAD + k]);
        #pragma unroll
        for (int n = 0; n < NPW; ++n) {
            float4 a = *reinterpret_cast<const float4*>(&rows[(myn0 + n) * DIM + k]);
            accB[n][0] += a.x * wr.x + a.y * wr.y + a.z * wr.z + a.w * wr.w;
            accB[n][1] += a.x * wz.x + a.y * wz.y + a.z * wz.z + a.w * wz.w;
            accB[n][2] += a.x * wn.x + a.y * wn.y + a.z * wn.z + a.w * wn.w;
        }
    }

    // ---- gates + output (overwrite aggr_out)
    const float bir = b_ih[lane], biz = b_ih[64 + lane], bin_ = b_ih[128 + lane];
    const float bhr = b_hh[lane], bhz = b_hh[64 + lane], bhn = b_hh[128 + lane];
    #pragma unroll
    for (int n = 0; n < NPW; ++n) {
        const int node = nb + myn0 + n;
        const float h = rows[(myn0 + n) * DIM + lane];   // rows holds `nodes`
        const float ir = accA[n][0] + bir, iz = accA[n][1] + biz, inn = accA[n][2] + bin_;
        const float hr = accB[n][0] + bhr, hz = accB[n][1] + bhz, hn = accB[n][2] + bhn;
        const float r = 1.f / (1.f + __expf(-(ir + hr)));
        const float z = 1.f / (1.f + __expf(-(iz + hz)));
        float t = inn + r * hn;
        t = fminf(fmaxf(t, -15.f), 15.f);
        const float e2 = __expf(2.f * t);
        const float ng = (e2 - 1.f) / (e2 + 1.f);
        aggr_out[(size_t)node * DIM + lane] = (1.f - z) * ng + z * h;
    }
}

// ---------------------------------------------------------------------------
extern "C" void kernel_launch(void* const* d_in, const int* in_sizes, int n_in,
                              void* d_out, int out_size, void* d_ws, size_t ws_size,
                              hipStream_t stream) {
    const float* edges     = (const float*)d_in[0];
    const float* nodes     = (const float*)d_in[1];
    const int*   receivers = (const int*)d_in[2];
    const float* w_ih      = (const float*)d_in[3];
    const float* w_hh      = (const float*)d_in[4];
    const float* b_ih      = (const float*)d_in[5];
    const float* b_hh      = (const float*)d_in[6];
    float* out = (float*)d_out;

    // workspace layout (ints, ~13.6 MB)
    int* ws      = (int*)d_ws;
    int* count   = ws;                       // 100000
    int* offsets = ws + N_NODES_C;           // 100000
    int* rank    = ws + 2 * N_NODES_C;       // 1.6M
    int* perm    = rank + N_EDGES_C;         // 1.6M
    int* bsums   = perm + N_EDGES_C;         // 128

    hipMemsetAsync(count, 0, N_NODES_C * sizeof(int), stream);

    hist_kernel<<<(N_EDGES_C + 255) / 256, 256, 0, stream>>>(receivers, count, rank);
    scan1_kernel<<<N_SCAN_BLOCKS, SCAN_B, 0, stream>>>(count, offsets, bsums);
    scan2_kernel<<<1, 128, 0, stream>>>(bsums);
    scan3_kernel<<<N_SCAN_BLOCKS, SCAN_B, 0, stream>>>(offsets, bsums);
    permw_kernel<<<(N_EDGES_C + 255) / 256, 256, 0, stream>>>(receivers, offsets, rank, perm);

    // aggr lives in d_out; gru_kernel consumes and overwrites it in place.
    gather_kernel<<<(N_NODES_C + 3) / 4, 256, 0, stream>>>(edges, perm, offsets, count, out);
    gru_kernel<<<N_NODES_C / NT, 256, 0, stream>>>(out, nodes, w_ih, w_hh, b_ih, b_hh);
}

// Round 4
// 325.435 us; speedup vs baseline: 4.6351x; 1.0161x over previous
//
#include <hip/hip_runtime.h>
#include <math.h>

#define N_NODES_C 100000
#define N_EDGES_C 1600000
#define DIM 64
#define G3 192
#define SCAN_B 1024
#define N_SCAN_BLOCKS ((N_NODES_C + SCAN_B - 1) / SCAN_B)   // 98

// ---------------------------------------------------------------------------
// Phase 1a: histogram receivers, record per-edge rank within its segment
// ---------------------------------------------------------------------------
__global__ void hist_kernel(const int* __restrict__ receivers,
                            int* __restrict__ count,
                            int* __restrict__ rank) {
    int e = blockIdx.x * blockDim.x + threadIdx.x;
    if (e >= N_EDGES_C) return;
    int r = receivers[e];
    rank[e] = __hip_atomic_fetch_add(&count[r], 1,
                                     __ATOMIC_RELAXED, __HIP_MEMORY_SCOPE_AGENT);
}

// ---------------------------------------------------------------------------
// Phase 1b: scan. offsets[] = block-local exclusive; bsums[] = per-block
// exclusive base (applied inline by consumers; no scan3 pass).
// ---------------------------------------------------------------------------
__global__ void scan1_kernel(const int* __restrict__ count,
                             int* __restrict__ offsets,
                             int* __restrict__ bsums) {
    __shared__ int wsum[16];
    const int gid  = blockIdx.x * SCAN_B + threadIdx.x;
    const int lane = threadIdx.x & 63;
    const int wv   = threadIdx.x >> 6;
    int c = (gid < N_NODES_C) ? count[gid] : 0;
    int x = c;
    #pragma unroll
    for (int o = 1; o < 64; o <<= 1) {
        int v = __shfl_up(x, o);
        if (lane >= o) x += v;
    }
    if (lane == 63) wsum[wv] = x;
    __syncthreads();
    if (wv == 0) {
        int s = (lane < 16) ? wsum[lane] : 0;
        #pragma unroll
        for (int o = 1; o < 16; o <<= 1) {
            int v = __shfl_up(s, o);
            if (lane >= o) s += v;
        }
        if (lane < 16) wsum[lane] = s;   // inclusive over waves
    }
    __syncthreads();
    int woff = (wv == 0) ? 0 : wsum[wv - 1];
    if (gid < N_NODES_C) offsets[gid] = woff + x - c;
    if (threadIdx.x == SCAN_B - 1) bsums[blockIdx.x] = wsum[15];
}

__global__ void scan2_kernel(int* __restrict__ bsums) {
    __shared__ int w0tot;
    const int i    = threadIdx.x;
    const int lane = threadIdx.x & 63;
    const int wv   = threadIdx.x >> 6;
    int c = (i < N_SCAN_BLOCKS) ? bsums[i] : 0;
    int x = c;
    #pragma unroll
    for (int o = 1; o < 64; o <<= 1) {
        int v = __shfl_up(x, o);
        if (lane >= o) x += v;
    }
    if (wv == 0 && lane == 63) w0tot = x;
    __syncthreads();
    int add = (wv == 1) ? w0tot : 0;
    if (i < N_SCAN_BLOCKS) bsums[i] = add + x - c;   // exclusive
}

// ---------------------------------------------------------------------------
// Phase 1c: write permutation (CSR edge lists); bsums applied inline
// ---------------------------------------------------------------------------
__global__ void permw_kernel(const int* __restrict__ receivers,
                             const int* __restrict__ offsets,
                             const int* __restrict__ bsums,
                             const int* __restrict__ rank,
                             int* __restrict__ perm) {
    int e = blockIdx.x * blockDim.x + threadIdx.x;
    if (e >= N_EDGES_C) return;
    int r = receivers[e];
    perm[offsets[r] + bsums[r >> 10] + rank[e]] = e;
}

// ---------------------------------------------------------------------------
// Phase 2: gather-aggregate. One wave per node. The node's perm segment is
// loaded with ONE coalesced vector load (pv = perm[start+lane]); edge indices
// are then extracted with v_readlane (register-only), so the 8 row-load
// chains issue back-to-back with no scalar-memory dependency in the loop.
// ---------------------------------------------------------------------------
__global__ __launch_bounds__(256)
void gather_kernel(const float* __restrict__ edges,
                   const int* __restrict__ perm,
                   const int* __restrict__ offsets,
                   const int* __restrict__ bsums,
                   const int* __restrict__ count,
                   float* __restrict__ aggr) {
    const int w    = (blockIdx.x << 2) | (threadIdx.x >> 6);
    const int lane = threadIdx.x & 63;
    if (w >= N_NODES_C) return;
    const int start = offsets[w] + bsums[w >> 10];
    const int cnt   = count[w];

    float a0 = 0.f, a1 = 0.f, a2 = 0.f, a3 = 0.f;
    float a4 = 0.f, a5 = 0.f, a6 = 0.f, a7 = 0.f;

    int done = 0;
    while (done < cnt) {
        const int chunk = min(cnt - done, 64);
        int pv = 0;
        if (lane < chunk) pv = perm[start + done + lane];
        int i = 0;
        for (; i + 8 <= chunk; i += 8) {
            const int e0 = __builtin_amdgcn_readlane(pv, i + 0);
            const int e1 = __builtin_amdgcn_readlane(pv, i + 1);
            const int e2 = __builtin_amdgcn_readlane(pv, i + 2);
            const int e3 = __builtin_amdgcn_readlane(pv, i + 3);
            const int e4 = __builtin_amdgcn_readlane(pv, i + 4);
            const int e5 = __builtin_amdgcn_readlane(pv, i + 5);
            const int e6 = __builtin_amdgcn_readlane(pv, i + 6);
            const int e7 = __builtin_amdgcn_readlane(pv, i + 7);
            a0 += edges[(size_t)e0 * DIM + lane];
            a1 += edges[(size_t)e1 * DIM + lane];
            a2 += edges[(size_t)e2 * DIM + lane];
            a3 += edges[(size_t)e3 * DIM + lane];
            a4 += edges[(size_t)e4 * DIM + lane];
            a5 += edges[(size_t)e5 * DIM + lane];
            a6 += edges[(size_t)e6 * DIM + lane];
            a7 += edges[(size_t)e7 * DIM + lane];
        }
        if (i + 4 <= chunk) {
            const int e0 = __builtin_amdgcn_readlane(pv, i + 0);
            const int e1 = __builtin_amdgcn_readlane(pv, i + 1);
            const int e2 = __builtin_amdgcn_readlane(pv, i + 2);
            const int e3 = __builtin_amdgcn_readlane(pv, i + 3);
            a0 += edges[(size_t)e0 * DIM + lane];
            a1 += edges[(size_t)e1 * DIM + lane];
            a2 += edges[(size_t)e2 * DIM + lane];
            a3 += edges[(size_t)e3 * DIM + lane];
            i += 4;
        }
        if (i + 2 <= chunk) {
            const int e0 = __builtin_amdgcn_readlane(pv, i + 0);
            const int e1 = __builtin_amdgcn_readlane(pv, i + 1);
            a4 += edges[(size_t)e0 * DIM + lane];
            a5 += edges[(size_t)e1 * DIM + lane];
            i += 2;
        }
        if (i < chunk) {
            const int e0 = __builtin_amdgcn_readlane(pv, i);
            a6 += edges[(size_t)e0 * DIM + lane];
        }
        done += chunk;
    }
    aggr[(size_t)w * DIM + lane] = ((a0 + a1) + (a2 + a3)) + ((a4 + a5) + (a6 + a7));
}

// ---------------------------------------------------------------------------
// Phase 3: GRU cell update. Block = 256 threads / 32 nodes. aggr_out (=d_out)
// is read (32 rows staged to LDS) then overwritten with the result.
// ---------------------------------------------------------------------------
#define NT 32
#define NPW 8
#define WPAD 68   // padded row stride (floats); 272B, 16B-aligned

__global__ __launch_bounds__(256, 2)
void gru_kernel(float* aggr_out,
                const float* __restrict__ nodes,
                const float* __restrict__ w_ih,
                const float* __restrict__ w_hh,
                const float* __restrict__ b_ih,
                const float* __restrict__ b_hh) {
    __shared__ float wlds[G3 * WPAD];   // 52.2 KB
    __shared__ float rows[NT * DIM];    // 8 KB

    const int tid  = threadIdx.x;
    const int lane = tid & 63;
    const int wave = tid >> 6;
    const int nb   = blockIdx.x * NT;
    const int myn0 = wave * NPW;

    float accA[NPW][3];
    float accB[NPW][3];

    // ---- stage w_ih + this block's aggr rows
    {
        const float4* src = reinterpret_cast<const float4*>(w_ih);
        #pragma unroll
        for (int i = 0; i < 12; ++i) {
            int t = tid + i * 256;               // 3072 float4s
            float4 v = src[t];
            int row = t >> 4;
            int col = (t & 15) << 2;
            *reinterpret_cast<float4*>(&wlds[row * WPAD + col]) = v;
        }
        #pragma unroll
        for (int i = 0; i < 2; ++i) {
            int t = tid + i * 256;               // 512 float4s
            int n = t >> 4, c = (t & 15) << 2;
            *reinterpret_cast<float4*>(&rows[n * DIM + c]) =
                *reinterpret_cast<const float4*>(&aggr_out[(size_t)(nb + n) * DIM + c]);
        }
    }
    __syncthreads();

    // ---- pass A: gi = aggr @ w_ih.T
    #pragma unroll
    for (int n = 0; n < NPW; ++n) { accA[n][0] = 0.f; accA[n][1] = 0.f; accA[n][2] = 0.f; }
    #pragma unroll 4
    for (int ks = 0; ks < 16; ++ks) {
        const int k = ks * 4;
        float4 wr = *reinterpret_cast<const float4*>(&wlds[lane * WPAD + k]);
        float4 wz = *reinterpret_cast<const float4*>(&wlds[(64 + lane) * WPAD + k]);
        float4 wn = *reinterpret_cast<const float4*>(&wlds[(128 + lane) * WPAD + k]);
        #pragma unroll
        for (int n = 0; n < NPW; ++n) {
            float4 a = *reinterpret_cast<const float4*>(&rows[(myn0 + n) * DIM + k]);
            accA[n][0] += a.x * wr.x + a.y * wr.y + a.z * wr.z + a.w * wr.w;
            accA[n][1] += a.x * wz.x + a.y * wz.y + a.z * wz.z + a.w * wz.w;
            accA[n][2] += a.x * wn.x + a.y * wn.y + a.z * wn.z + a.w * wn.w;
        }
    }
    __syncthreads();

    // ---- restage: w_hh + node rows
    {
        const float4* src = reinterpret_cast<const float4*>(w_hh);
        #pragma unroll
        for (int i = 0; i < 12; ++i) {
            int t = tid + i * 256;
            float4 v = src[t];
            int row = t >> 4;
            int col = (t & 15) << 2;
            *reinterpret_cast<float4*>(&wlds[row * WPAD + col]) = v;
        }
        #pragma unroll
        for (int i = 0; i < 2; ++i) {
            int t = tid + i * 256;
            int n = t >> 4, c = (t & 15) << 2;
            *reinterpret_cast<float4*>(&rows[n * DIM + c]) =
                *reinterpret_cast<const float4*>(&nodes[(size_t)(nb + n) * DIM + c]);
        }
    }
    __syncthreads();

    // ---- pass B: gh = nodes @ w_hh.T
    #pragma unroll
    for (int n = 0; n < NPW; ++n) { accB[n][0] = 0.f; accB[n][1] = 0.f; accB[n][2] = 0.f; }
    #pragma unroll 4
    for (int ks = 0; ks < 16; ++ks) {
        const int k = ks * 4;
        float4 wr = *reinterpret_cast<const float4*>(&wlds[lane * WPAD + k]);
        float4 wz = *reinterpret_cast<const float4*>(&wlds[(64 + lane) * WPAD + k]);
        float4 wn = *reinterpret_cast<const float4*>(&wlds[(128 + lane) * WPAD + k]);
        #pragma unroll
        for (int n = 0; n < NPW; ++n) {
            float4 a = *reinterpret_cast<const float4*>(&rows[(myn0 + n) * DIM + k]);
            accB[n][0] += a.x * wr.x + a.y * wr.y + a.z * wr.z + a.w * wr.w;
            accB[n][1] += a.x * wz.x + a.y * wz.y + a.z * wz.z + a.w * wz.w;
            accB[n][2] += a.x * wn.x + a.y * wn.y + a.z * wn.z + a.w * wn.w;
        }
    }

    // ---- gates + output (overwrite aggr_out)
    const float bir = b_ih[lane], biz = b_ih[64 + lane], bin_ = b_ih[128 + lane];
    const float bhr = b_hh[lane], bhz = b_hh[64 + lane], bhn = b_hh[128 + lane];
    #pragma unroll
    for (int n = 0; n < NPW; ++n) {
        const int node = nb + myn0 + n;
        const float h = rows[(myn0 + n) * DIM + lane];   // rows holds `nodes`
        const float ir = accA[n][0] + bir, iz = accA[n][1] + biz, inn = accA[n][2] + bin_;
        const float hr = accB[n][0] + bhr, hz = accB[n][1] + bhz, hn = accB[n][2] + bhn;
        const float r = 1.f / (1.f + __expf(-(ir + hr)));
        const float z = 1.f / (1.f + __expf(-(iz + hz)));
        float t = inn + r * hn;
        t = fminf(fmaxf(t, -15.f), 15.f);
        const float e2 = __expf(2.f * t);
        const float ng = (e2 - 1.f) / (e2 + 1.f);
        aggr_out[(size_t)node * DIM + lane] = (1.f - z) * ng + z * h;
    }
}

// ---------------------------------------------------------------------------
extern "C" void kernel_launch(void* const* d_in, const int* in_sizes, int n_in,
                              void* d_out, int out_size, void* d_ws, size_t ws_size,
                              hipStream_t stream) {
    const float* edges     = (const float*)d_in[0];
    const float* nodes     = (const float*)d_in[1];
    const int*   receivers = (const int*)d_in[2];
    const float* w_ih      = (const float*)d_in[3];
    const float* w_hh      = (const float*)d_in[4];
    const float* b_ih      = (const float*)d_in[5];
    const float* b_hh      = (const float*)d_in[6];
    float* out = (float*)d_out;

    // workspace layout (ints, ~13.6 MB)
    int* ws      = (int*)d_ws;
    int* count   = ws;                       // 100000
    int* offsets = ws + N_NODES_C;           // 100000
    int* rank    = ws + 2 * N_NODES_C;       // 1.6M
    int* perm    = rank + N_EDGES_C;         // 1.6M
    int* bsums   = perm + N_EDGES_C;         // 128

    hipMemsetAsync(count, 0, N_NODES_C * sizeof(int), stream);

    hist_kernel<<<(N_EDGES_C + 255) / 256, 256, 0, stream>>>(receivers, count, rank);
    scan1_kernel<<<N_SCAN_BLOCKS, SCAN_B, 0, stream>>>(count, offsets, bsums);
    scan2_kernel<<<1, 128, 0, stream>>>(bsums);
    permw_kernel<<<(N_EDGES_C + 255) / 256, 256, 0, stream>>>(receivers, offsets, bsums, rank, perm);

    // aggr lives in d_out; gru_kernel consumes and overwrites it in place.
    gather_kernel<<<(N_NODES_C + 3) / 4, 256, 0, stream>>>(edges, perm, offsets, bsums, count, out);
    gru_kernel<<<N_NODES_C / NT, 256, 0, stream>>>(out, nodes, w_ih, w_hh, b_ih, b_hh);
}